// Round 5
// baseline (196.804 us; speedup 1.0000x reference)
//
#include <hip/hip_runtime.h>
#include <hip/hip_bf16.h>

// Problem constants
#define BATCH 2
#define SLEN 2048
#define DMODEL 1024
#define NHEADS 16
#define NKV 4
#define DHEAD 64
#define WINDOW 256
#define NGLOBAL 4

typedef __attribute__((ext_vector_type(8))) short short8;
typedef __attribute__((ext_vector_type(4))) float floatx4;

__device__ __forceinline__ ushort f2bf(float f) {
    __hip_bfloat16 h = __float2bfloat16(f);
    return *reinterpret_cast<ushort*>(&h);
}
__device__ __forceinline__ float bf2f(ushort u) {
    __hip_bfloat16 h = *reinterpret_cast<__hip_bfloat16*>(&u);
    return __bfloat162float(h);
}
// dtype flag: cos[0]==1.0f exactly. fp32 -> low16 of first dword == 0x0000;
// bf16 pair -> low16 == 0x3F80. Wave-uniform branch, graph-capture safe.
__device__ __forceinline__ bool is_bf16_inputs(const uint* cosu) {
    return (cosu[0] & 0xFFFFu) != 0u;
}
// async global->LDS, 16B per lane. LDS dest is wave-uniform base + lane*16.
__device__ __forceinline__ void gload_lds16(const ushort* g, ushort* l) {
    __builtin_amdgcn_global_load_lds(
        (const __attribute__((address_space(1))) void*)g,
        (__attribute__((address_space(3))) void*)l, 16, 0, 0);
}

// ---------------- fused input canonicalization ----------------
// y==0: x -> bf16 (vectorized x8). y==1: cos|sin -> f32.
__global__ __launch_bounds__(256) void cvt_inputs(const void* __restrict__ x,
                                                  const void* __restrict__ cosi,
                                                  const void* __restrict__ sini,
                                                  ushort* __restrict__ xb,
                                                  float* __restrict__ cosf,
                                                  float* __restrict__ sinf,
                                                  const uint* __restrict__ cosu)
{
    const bool isbf = is_bf16_inputs(cosu);
    if (blockIdx.y == 0) {
        size_t i = (size_t)blockIdx.x * 256 + threadIdx.x;   // 8-elem chunk, 524288 total
        size_t e = i * 8;
        if (isbf) {
            *reinterpret_cast<uint4*>(xb + e) = reinterpret_cast<const uint4*>(x)[i];
        } else {
            const float* f = reinterpret_cast<const float*>(x) + e;
            ushort o[8];
#pragma unroll
            for (int j = 0; j < 8; ++j) o[j] = f2bf(f[j]);
            *reinterpret_cast<uint4*>(xb + e) = *reinterpret_cast<uint4*>(o);
        }
    } else {
        int i = blockIdx.x * 256 + threadIdx.x;
        if (i >= 2 * SLEN * 32) return;
        const void* src = (i < SLEN * 32) ? cosi : sini;
        float* dst = (i < SLEN * 32) ? cosf : sinf;
        int e = i & (SLEN * 32 - 1);
        dst[e] = isbf ? bf2f(reinterpret_cast<const ushort*>(src)[e])
                      : reinterpret_cast<const float*>(src)[e];
    }
}

// ---------------- fused weight transpose: all 4 weights -> K-major bf16 ----------------
__global__ __launch_bounds__(256) void prep_weights(const void* __restrict__ Wq,
                                                    const void* __restrict__ Wk,
                                                    const void* __restrict__ Wv,
                                                    const void* __restrict__ Wo,
                                                    ushort* __restrict__ Wt,
                                                    ushort* __restrict__ Wot,
                                                    const uint* __restrict__ cosu)
{
    const bool isbf = is_bf16_inputs(cosu);
    const int z = blockIdx.z;
    const void* src; ushort* dst; int C;
    if (z == 0)      { src = Wq; dst = Wt;                        C = 1024; }
    else if (z == 1) { src = Wk; dst = Wt + (size_t)1024 * 1024;  C = 256; }
    else if (z == 2) { src = Wv; dst = Wt + (size_t)1280 * 1024;  C = 256; }
    else             { src = Wo; dst = Wot;                       C = 1024; }
    const int bx = blockIdx.x * 32;
    if (bx >= C) return;
    const int by = blockIdx.y * 32;
    __shared__ ushort t[32][33];
    const int tx = threadIdx.x & 31, ty = threadIdx.x >> 5;
#pragma unroll
    for (int j = 0; j < 32; j += 8) {
        size_t idx = (size_t)(by + ty + j) * C + bx + tx;
        t[ty + j][tx] = isbf ? reinterpret_cast<const ushort*>(src)[idx]
                             : f2bf(reinterpret_cast<const float*>(src)[idx]);
    }
    __syncthreads();
#pragma unroll
    for (int j = 0; j < 32; j += 8)
        dst[(size_t)(bx + ty + j) * 1024 + by + tx] = t[tx][ty + j];
}

// ---------------- bf16 slab transpose: per-slab (R x C) -> (C x R) ----------------
__global__ __launch_bounds__(256) void transpose_slab_bf16(const ushort* __restrict__ in,
                                                           ushort* __restrict__ out,
                                                           int R, int C)
{
    __shared__ ushort t[32][33];
    const ushort* ip = in + (size_t)blockIdx.z * R * C;
    ushort* op = out + (size_t)blockIdx.z * R * C;
    int bx = blockIdx.x * 32, by = blockIdx.y * 32;
    int tx = threadIdx.x & 31, ty = threadIdx.x >> 5;
#pragma unroll
    for (int j = 0; j < 32; j += 8)
        t[ty + j][tx] = ip[(size_t)(by + ty + j) * C + bx + tx];
    __syncthreads();
#pragma unroll
    for (int j = 0; j < 32; j += 8)
        op[(size_t)(bx + ty + j) * R + by + tx] = t[tx][ty + j];
}

// ---------------- split-K m97-style MFMA GEMM ----------------
// P[z][M][N] (f32) = A[M, z*Kh:(z+1)*Kh] x Bt[N, same]^T. 128x128 tile, BK=64,
// 4 waves 2x2, each wave 64x64 = 4x4 frags of 16x16x32. global_load_lds width-16.
// Grid (N/128, M/128, 2) doubles block count vs monolithic-K: occupancy was the
// R4 limiter (9.6% at 384 blocks, MfmaUtil 6.7%).
__global__ __launch_bounds__(256) void gemm128_sk(const ushort* __restrict__ A,
                                                  const ushort* __restrict__ Bt,
                                                  float* __restrict__ P,
                                                  int M, int N, int Kh)
{
    __shared__ ushort lsA[128 * 64];
    __shared__ ushort lsB[128 * 64];
    const int tid = threadIdx.x;
    const int lane = tid & 63, w = tid >> 6;
    const int ln15 = lane & 15, quad = lane >> 4;
    const int wm = w >> 1, wn = w & 1;
    const int rm = blockIdx.y * 128, cn = blockIdx.x * 128;
    const int kbeg = blockIdx.z * Kh;
    float* Pz = P + (size_t)blockIdx.z * M * N;

    floatx4 acc[4][4];
#pragma unroll
    for (int i = 0; i < 4; ++i)
#pragma unroll
        for (int j = 0; j < 4; ++j) acc[i][j] = (floatx4){0.f, 0.f, 0.f, 0.f};

    const size_t K = blockDim.y == 1 ? 0 : 0;  // (silence unused warnings pattern)
    const int Kfull = Kh * 2;

    for (int k0 = kbeg; k0 < kbeg + Kh; k0 += 64) {
        __syncthreads();
#pragma unroll
        for (int i = 0; i < 4; ++i) {
            const int c = (i * 4 + w) * 64 + lane;       // chunk id 0..1023
            const int row = c >> 3, col = (c & 7) * 8;   // [128 rows][64 cols]
            gload_lds16(&A[(size_t)(rm + row) * Kfull + k0 + col], &lsA[(i * 4 + w) * 512]);
            gload_lds16(&Bt[(size_t)(cn + row) * Kfull + k0 + col], &lsB[(i * 4 + w) * 512]);
        }
        __syncthreads();
#pragma unroll
        for (int kk = 0; kk < 64; kk += 32) {
            short8 af[4], bf[4];
#pragma unroll
            for (int i = 0; i < 4; ++i) {
                af[i] = *reinterpret_cast<const short8*>(&lsA[(wm * 64 + i * 16 + ln15) * 64 + kk + quad * 8]);
                bf[i] = *reinterpret_cast<const short8*>(&lsB[(wn * 64 + i * 16 + ln15) * 64 + kk + quad * 8]);
            }
#pragma unroll
            for (int i = 0; i < 4; ++i)
#pragma unroll
                for (int j = 0; j < 4; ++j)
                    acc[i][j] = __builtin_amdgcn_mfma_f32_16x16x32_bf16(af[i], bf[j], acc[i][j], 0, 0, 0);
        }
    }

#pragma unroll
    for (int i = 0; i < 4; ++i) {
#pragma unroll
        for (int r = 0; r < 4; ++r) {
            const int grow = rm + wm * 64 + i * 16 + quad * 4 + r;
#pragma unroll
            for (int j = 0; j < 4; ++j) {
                const int gcol = cn + wn * 64 + j * 16 + ln15;
                Pz[(size_t)grow * N + gcol] = acc[i][j][r];
            }
        }
    }
}

// ---------------- split-K reduce -> output (dtype-matched) ----------------
__global__ __launch_bounds__(256) void reduce_out(const float* __restrict__ P,
                                                  void* __restrict__ out,
                                                  size_t mn4,
                                                  const uint* __restrict__ cosu)
{
    const bool isbf = is_bf16_inputs(cosu);
    size_t i = (size_t)blockIdx.x * 256 + threadIdx.x;
    if (i >= mn4) return;
    const size_t mn = mn4 * 4;
    floatx4 a = *reinterpret_cast<const floatx4*>(P + i * 4);
    floatx4 b = *reinterpret_cast<const floatx4*>(P + mn + i * 4);
    floatx4 s = a + b;
    if (isbf) {
        ushort o[4];
#pragma unroll
        for (int j = 0; j < 4; ++j) o[j] = f2bf(s[j]);
        reinterpret_cast<uint2*>(out)[i] = *reinterpret_cast<uint2*>(o);
    } else {
        reinterpret_cast<floatx4*>(out)[i] = s;
    }
}

// ---------------- L2 normalize + RoPE (+ split-K reduce) -> bf16 Q / K / V ----------------
// qkvp: f32 partials [2][4096][1536]. One wave per (b,s,head-slot); 4 waves/block.
__global__ __launch_bounds__(256) void norm_rope(const float* __restrict__ qkvp,
                                                 const float* __restrict__ cosf,
                                                 const float* __restrict__ sinf,
                                                 ushort* __restrict__ Qb,
                                                 ushort* __restrict__ Kg,
                                                 ushort* __restrict__ Vb)
{
    const int lane = threadIdx.x & 63;
    const int g = blockIdx.x * 4 + (threadIdx.x >> 6);
    const int hh = g % 24;                    // 0..15 q, 16..19 k, 20..23 v
    const int s = (g / 24) & (SLEN - 1);
    const int b = g / (24 * SLEN);
    const size_t row = (size_t)(b * SLEN + s) * 1536;
    const size_t MN = (size_t)4096 * 1536;

    if (hh >= 20) {
        int hkv = hh - 20;
        size_t idx = row + 1280 + hkv * 64 + lane;
        Vb[((size_t)((b * NKV + hkv) * SLEN + s)) * 64 + lane] = f2bf(qkvp[idx] + qkvp[MN + idx]);
        return;
    }
    const bool isq = hh < 16;
    const int col = isq ? hh * 64 : 1024 + (hh - 16) * 64;
    const size_t idx = row + col + lane;
    float v = qkvp[idx] + qkvp[MN + idx];
    float ss = v * v;
#pragma unroll
    for (int off = 32; off; off >>= 1) ss += __shfl_xor(ss, off, 64);
    float nv = v / (sqrtf(ss) + 1e-8f);
    float p = __shfl(nv, lane ^ 32, 64);
    int dh = lane & 31;
    float c = cosf[s * 32 + dh];
    float sn = sinf[s * 32 + dh];
    float o = (lane < 32) ? (nv * c - p * sn) : (p * sn + nv * c);
    if (isq) Qb[((size_t)((b * NHEADS + hh) * SLEN + s)) * 64 + lane] = f2bf(o);
    else {
        int hkv = hh - 16;
        Kg[((size_t)((b * NKV + hkv) * SLEN + s)) * 64 + lane] = f2bf(o);
    }
}

// ---------------- MFMA windowed flash attention, 64-key chunks ----------------
// Block = 64 queries of one (b,h): 4 waves x 16 q. Chunks of 64 keys over
// [align64(q0-255), q0+63] plus one global chunk (keys 0..3) when excluded.
// No running max: q,k unit vectors => |score*scale| <= 0.125, exp safe.
// softcap-exp: st = 15 - 30/(e^{2*sv/15}+1); p = exp(st). (|tanh arg| <= 0.0083)
__global__ __launch_bounds__(256) void attn_mfma(const ushort* __restrict__ Qb,
                                                 const ushort* __restrict__ Kg,
                                                 const ushort* __restrict__ Vtg,
                                                 ushort* __restrict__ ctx)
{
    __shared__ ushort Ks[64 * 72];      // [64 keys][64 dims], stride 72
    __shared__ ushort Vs[64 * 72];      // [64 dims][64 keys], stride 72
    __shared__ ushort Ps[4][16 * 72];   // per-wave P: [16 q][64 k], stride 72

    const int tid = threadIdx.x;
    const int lane = tid & 63, w = tid >> 6;
    const int ln15 = lane & 15, quad = lane >> 4;
    const int bid = blockIdx.x;
    const int qt = bid & 31, bh = bid >> 5;
    const int h = bh & (NHEADS - 1), b = bh >> 4, hkv = h >> 2;
    const int q0 = qt * 64;
    const int qw = q0 + w * 16;

    const ushort* Qrow = Qb + ((size_t)bh * SLEN + qw) * 64;
    const ushort* Kbase = Kg + (size_t)(b * NKV + hkv) * SLEN * 64;
    const ushort* Vbase = Vtg + (size_t)(b * NKV + hkv) * 64 * SLEN;

    short8 qf0 = *reinterpret_cast<const short8*>(Qrow + (size_t)ln15 * 64 + quad * 8);
    short8 qf1 = *reinterpret_cast<const short8*>(Qrow + (size_t)ln15 * 64 + 32 + quad * 8);

    floatx4 O0 = {0,0,0,0}, O1 = {0,0,0,0}, O2 = {0,0,0,0}, O3 = {0,0,0,0};
    float lp[4] = {0.f, 0.f, 0.f, 0.f};

    int kminA = q0 - (WINDOW - 1); if (kminA < 0) kminA = 0;
    kminA &= ~63;
    const int gmax = kminA < NGLOBAL ? kminA : NGLOBAL;
    const int nc = (q0 + 64 - kminA) >> 6;

    for (int c = (gmax > 0 ? -1 : 0); c < nc; ++c) {
        const int kbase = (c < 0) ? 0 : kminA + c * 64;
        __syncthreads();
#pragma unroll
        for (int j = 0; j < 2; ++j) {
            const int c2 = tid + j * 256;                 // chunk 0..511
            const int row = c2 >> 3, col = (c2 & 7) * 8;
            *reinterpret_cast<uint4*>(&Ks[row * 72 + col]) =
                *reinterpret_cast<const uint4*>(&Kbase[(size_t)(kbase + row) * 64 + col]);
            *reinterpret_cast<uint4*>(&Vs[row * 72 + col]) =
                *reinterpret_cast<const uint4*>(&Vbase[(size_t)row * SLEN + kbase + col]);
        }
        __syncthreads();

#pragma unroll
        for (int t = 0; t < 4; ++t) {
            short8 kf0 = *reinterpret_cast<const short8*>(&Ks[(t * 16 + ln15) * 72 + quad * 8]);
            short8 kf1 = *reinterpret_cast<const short8*>(&Ks[(t * 16 + ln15) * 72 + 32 + quad * 8]);
            floatx4 sc = {0,0,0,0};
            sc = __builtin_amdgcn_mfma_f32_16x16x32_bf16(qf0, kf0, sc, 0, 0, 0);
            sc = __builtin_amdgcn_mfma_f32_16x16x32_bf16(qf1, kf1, sc, 0, 0, 0);
            const int k = kbase + t * 16 + ln15;
#pragma unroll
            for (int r = 0; r < 4; ++r) {
                const int q = qw + quad * 4 + r;
                const bool valid = (c < 0) ? (k < gmax)
                                           : (k <= q && (k + WINDOW > q || k < NGLOBAL));
                float sv = sc[r] * 0.125f;                     // ATTN_SCALE
                float e2 = __expf(sv * 0.13333333f);           // e^{2*sv/15}
                float st = 15.f - 30.f * __builtin_amdgcn_rcpf(e2 + 1.f);
                ushort eb = valid ? f2bf(__expf(st)) : (ushort)0;
                Ps[w][(quad * 4 + r) * 72 + t * 16 + ln15] = eb;
                lp[r] += bf2f(eb);
            }
        }
        // P -> A-frag (in-wave LDS round trip; DS ops are in-order per wave)
        short8 af0 = *reinterpret_cast<const short8*>(&Ps[w][ln15 * 72 + quad * 8]);
        short8 af1 = *reinterpret_cast<const short8*>(&Ps[w][ln15 * 72 + 32 + quad * 8]);
#pragma unroll
        for (int n = 0; n < 4; ++n) {
            short8 vf0 = *reinterpret_cast<const short8*>(&Vs[(n * 16 + ln15) * 72 + quad * 8]);
            short8 vf1 = *reinterpret_cast<const short8*>(&Vs[(n * 16 + ln15) * 72 + 32 + quad * 8]);
            floatx4 On = (n == 0) ? O0 : (n == 1) ? O1 : (n == 2) ? O2 : O3;
            On = __builtin_amdgcn_mfma_f32_16x16x32_bf16(af0, vf0, On, 0, 0, 0);
            On = __builtin_amdgcn_mfma_f32_16x16x32_bf16(af1, vf1, On, 0, 0, 0);
            if (n == 0) O0 = On; else if (n == 1) O1 = On; else if (n == 2) O2 = On; else O3 = On;
        }
    }

#pragma unroll
    for (int r = 0; r < 4; ++r) {
#pragma unroll
        for (int off = 1; off < 16; off <<= 1)
            lp[r] += __shfl_xor(lp[r], off, 64);
        const float inv = __builtin_amdgcn_rcpf(lp[r]);
        const int q = qw + quad * 4 + r;
        ushort* crow = ctx + ((size_t)(b * SLEN + q)) * DMODEL + h * 64 + ln15;
        crow[0]  = f2bf(O0[r] * inv);
        crow[16] = f2bf(O1[r] * inv);
        crow[32] = f2bf(O2[r] * inv);
        crow[48] = f2bf(O3[r] * inv);
    }
}

// ---------------- launch ----------------
extern "C" void kernel_launch(void* const* d_in, const int* in_sizes, int n_in,
                              void* d_out, int out_size, void* d_ws, size_t ws_size,
                              hipStream_t stream)
{
    (void)in_sizes; (void)n_in; (void)out_size; (void)ws_size;
    const void* x = d_in[0];
    const void* cosi = d_in[1];
    const void* sini = d_in[2];
    const uint* cosu = (const uint*)d_in[1];
    // d_in[3] = mask: computed analytically, not read
    const void* Wq = d_in[4];
    const void* Wk = d_in[5];
    const void* Wv = d_in[6];
    const void* Wo = d_in[7];

    // workspace layout (~120 MB)
    ushort* xb = (ushort*)d_ws;                        // [4096][1024] bf16
    ushort* Wt = xb + (size_t)4096 * 1024;             // [1536][1024] bf16
    ushort* Wot = Wt + (size_t)1536 * 1024;            // [1024][1024] bf16
    float* cosf = (float*)(Wot + (size_t)1024 * 1024); // [2048*32] f32
    float* sinf = cosf + (size_t)SLEN * 32;
    float* qkvp = sinf + (size_t)SLEN * 32;            // [2][4096][1536] f32 partials
    ushort* Qbf = (ushort*)(qkvp + (size_t)2 * 4096 * 1536);   // [2*16*2048][64]
    ushort* Kgf = Qbf + (size_t)BATCH * NHEADS * SLEN * 64;    // [2*4*2048][64]
    ushort* Vbf = Kgf + (size_t)BATCH * NKV * SLEN * 64;       // [2*4*2048][64]
    ushort* Vtg = Vbf + (size_t)BATCH * NKV * SLEN * 64;       // [2*4][64][2048]
    ushort* ctx = Vtg + (size_t)BATCH * NKV * 64 * SLEN;       // [4096][1024]
    float* outp = (float*)(ctx + (size_t)4096 * 1024);         // [2][4096][1024] f32 partials

    // 0) canonicalize inputs (x->bf16, cos/sin->f32), dtype from cos[0]
    cvt_inputs<<<dim3(2048, 2), 256, 0, stream>>>(x, cosi, sini, xb, cosf, sinf, cosu);

    // 1) all weight transposes in one dispatch
    prep_weights<<<dim3(32, 32, 4), 256, 0, stream>>>(Wq, Wk, Wv, Wo, Wt, Wot, cosu);

    // 2) fused QKV projection, split-K=2 -> f32 partials (768 blocks)
    gemm128_sk<<<dim3(12, 32, 2), 256, 0, stream>>>(xb, Wt, qkvp, 4096, 1536, 512);

    // 3) l2-normalize + rope (+ split-K reduce) -> bf16 Q/K/V
    norm_rope<<<dim3(BATCH * SLEN * 24 / 4), 256, 0, stream>>>(qkvp, cosf, sinf, Qbf, Kgf, Vbf);

    // 4) V -> V^T per (b,hkv) slab
    transpose_slab_bf16<<<dim3(2, 64, BATCH * NKV), 256, 0, stream>>>(Vbf, Vtg, SLEN, 64);

    // 5) MFMA windowed attention
    attn_mfma<<<dim3(BATCH * NHEADS * SLEN / 64), 256, 0, stream>>>(Qbf, Kgf, Vtg, ctx);

    // 6) output projection, split-K=2 -> f32 partials (512 blocks)
    gemm128_sk<<<dim3(8, 32, 2), 256, 0, stream>>>(ctx, Wot, outp, 4096, 1024, 512);

    // 7) reduce partials -> d_out (dtype-matched)
    reduce_out<<<dim3(4096), 256, 0, stream>>>(outp, d_out, (size_t)4096 * 1024 / 4, cosu);
}

// Round 6
// 166.089 us; speedup vs baseline: 1.1849x; 1.1849x over previous
//
#include <hip/hip_runtime.h>
#include <hip/hip_bf16.h>

// Problem constants
#define BATCH 2
#define SLEN 2048
#define DMODEL 1024
#define NHEADS 16
#define NKV 4
#define DHEAD 64
#define WINDOW 256
#define NGLOBAL 4

typedef __attribute__((ext_vector_type(8))) short short8;
typedef __attribute__((ext_vector_type(4))) float floatx4;

__device__ __forceinline__ ushort f2bf(float f) {
    __hip_bfloat16 h = __float2bfloat16(f);
    return *reinterpret_cast<ushort*>(&h);
}
__device__ __forceinline__ float bf2f(ushort u) {
    __hip_bfloat16 h = *reinterpret_cast<__hip_bfloat16*>(&u);
    return __bfloat162float(h);
}
// dtype flag: cos[0]==1.0f exactly. fp32 -> low16 of first dword == 0x0000;
// bf16 pair -> low16 == 0x3F80. Wave-uniform branch, graph-capture safe.
__device__ __forceinline__ bool is_bf16_inputs(const uint* cosu) {
    return (cosu[0] & 0xFFFFu) != 0u;
}
// async global->LDS, 16B per lane. LDS dest is wave-uniform base + lane*16.
__device__ __forceinline__ void gload_lds16(const ushort* g, ushort* l) {
    __builtin_amdgcn_global_load_lds(
        (const __attribute__((address_space(1))) void*)g,
        (__attribute__((address_space(3))) void*)l, 16, 0, 0);
}

// ---------------- prep: canonicalize x/cos/sin + transpose all weights (1 dispatch) ----------------
// flat block ranges: [0,2048) x->bf16 x8; [2048,2560) cos/sin->f32;
// [2560,3584) Wq^T; [3584,3840) Wk^T; [3840,4096) Wv^T; [4096,5120) Wo^T.
__global__ __launch_bounds__(256) void prep_all(const void* __restrict__ x,
                                                const void* __restrict__ cosi,
                                                const void* __restrict__ sini,
                                                const void* __restrict__ Wq,
                                                const void* __restrict__ Wk,
                                                const void* __restrict__ Wv,
                                                const void* __restrict__ Wo,
                                                ushort* __restrict__ xb,
                                                float* __restrict__ cosf,
                                                float* __restrict__ sinf,
                                                ushort* __restrict__ Wt,
                                                ushort* __restrict__ Wot,
                                                const uint* __restrict__ cosu)
{
    __shared__ ushort t[32][33];
    const bool isbf = is_bf16_inputs(cosu);
    const int bid = blockIdx.x, tid = threadIdx.x;
    if (bid < 2048) {
        size_t i = (size_t)bid * 256 + tid;     // 8-elem chunks, 524288 total
        size_t e = i * 8;
        if (isbf) {
            *reinterpret_cast<uint4*>(xb + e) = reinterpret_cast<const uint4*>(x)[i];
        } else {
            const float* f = reinterpret_cast<const float*>(x) + e;
            ushort o[8];
#pragma unroll
            for (int j = 0; j < 8; ++j) o[j] = f2bf(f[j]);
            *reinterpret_cast<uint4*>(xb + e) = *reinterpret_cast<uint4*>(o);
        }
        return;
    }
    if (bid < 2560) {
        int i = (bid - 2048) * 256 + tid;       // 0..131071
        const void* src = (i < SLEN * 32) ? cosi : sini;
        float* dst = (i < SLEN * 32) ? cosf : sinf;
        int e = i & (SLEN * 32 - 1);
        dst[e] = isbf ? bf2f(reinterpret_cast<const ushort*>(src)[e])
                      : reinterpret_cast<const float*>(src)[e];
        return;
    }
    const void* src; ushort* dst; int C, tl;
    if (bid < 3584)      { src = Wq; dst = Wt;                       C = 1024; tl = bid - 2560; }
    else if (bid < 3840) { src = Wk; dst = Wt + (size_t)1024 * 1024; C = 256;  tl = bid - 3584; }
    else if (bid < 4096) { src = Wv; dst = Wt + (size_t)1280 * 1024; C = 256;  tl = bid - 3840; }
    else                 { src = Wo; dst = Wot;                      C = 1024; tl = bid - 4096; }
    const int nbx = C >> 5;
    const int bx = (tl % nbx) * 32, by = (tl / nbx) * 32;
    const int tx = tid & 31, ty = tid >> 5;
#pragma unroll
    for (int j = 0; j < 32; j += 8) {
        size_t idx = (size_t)(by + ty + j) * C + bx + tx;
        t[ty + j][tx] = isbf ? reinterpret_cast<const ushort*>(src)[idx]
                             : f2bf(reinterpret_cast<const float*>(src)[idx]);
    }
    __syncthreads();
#pragma unroll
    for (int j = 0; j < 32; j += 8)
        dst[(size_t)(bx + ty + j) * 1024 + by + tx] = t[tx][ty + j];
}

// ---------------- QKV GEMM with fused l2norm+RoPE+relayout epilogue ----------------
// Tile 128M x 64N (one head-slot per block), BK=64, grid (24 slots, 32 M-tiles) = 768 blocks.
// 4 waves, wave w = rows w*32..w*32+31, all 64 cols: acc[2][4] frags of 16x16x32.
// N-tile == head => block holds the full head vector per row at epilogue:
//   Q/K: l2norm (reduce over 4 regs + 16 lanes), RoPE (pair j<->j^2, same lane), -> Qb/Kg.
//   V:   raw bf16, LDS-transposed -> Vtg [d][s].
// A-frag: A[m=lane&15][k=quad*8+j]; B-frag: Bt[n][k]; C/D: row=quad*4+reg, col=lane&15.
__global__ __launch_bounds__(256) void gemm_qkv_nr(const ushort* __restrict__ A,
                                                   const ushort* __restrict__ Bt,
                                                   const float* __restrict__ cosf,
                                                   const float* __restrict__ sinf,
                                                   ushort* __restrict__ Qb,
                                                   ushort* __restrict__ Kg,
                                                   ushort* __restrict__ Vtg)
{
    __shared__ __align__(16) ushort buf[12288];   // lsA 8192 | lsB 4096; epilogue reuses
    ushort* lsA = buf;
    ushort* lsB = buf + 8192;
    const int tid = threadIdx.x;
    const int lane = tid & 63, w = tid >> 6;
    const int ln15 = lane & 15, quad = lane >> 4;
    const int z = blockIdx.x;                     // head-slot 0..23
    const int rm = blockIdx.y * 128;
    const int cn = z * 64;

    floatx4 acc[2][4];
#pragma unroll
    for (int i = 0; i < 2; ++i)
#pragma unroll
        for (int j = 0; j < 4; ++j) acc[i][j] = (floatx4){0.f, 0.f, 0.f, 0.f};

    for (int k0 = 0; k0 < 1024; k0 += 64) {
        __syncthreads();
#pragma unroll
        for (int i = 0; i < 4; ++i) {             // A: 128x64 = 16 wave-calls
            const int c = (i * 4 + w) * 64 + lane;
            const int row = c >> 3, col = (c & 7) * 8;
            gload_lds16(&A[(size_t)(rm + row) * 1024 + k0 + col], &lsA[(i * 4 + w) * 512]);
        }
#pragma unroll
        for (int i = 0; i < 2; ++i) {             // B: 64x64 = 8 wave-calls
            const int c = (w * 2 + i) * 64 + lane;
            const int row = c >> 3, col = (c & 7) * 8;
            gload_lds16(&Bt[(size_t)(cn + row) * 1024 + k0 + col], &lsB[(w * 2 + i) * 512]);
        }
        __syncthreads();
#pragma unroll
        for (int kk = 0; kk < 64; kk += 32) {
            short8 af[2], bv[4];
#pragma unroll
            for (int i = 0; i < 2; ++i)
                af[i] = *reinterpret_cast<const short8*>(&lsA[(w * 32 + i * 16 + ln15) * 64 + kk + quad * 8]);
#pragma unroll
            for (int j = 0; j < 4; ++j)
                bv[j] = *reinterpret_cast<const short8*>(&lsB[(j * 16 + ln15) * 64 + kk + quad * 8]);
#pragma unroll
            for (int i = 0; i < 2; ++i)
#pragma unroll
                for (int j = 0; j < 4; ++j)
                    acc[i][j] = __builtin_amdgcn_mfma_f32_16x16x32_bf16(af[i], bv[j], acc[i][j], 0, 0, 0);
        }
    }

    __syncthreads();                              // lsA/lsB free now
    const int b = rm >> 11, s0 = rm & (SLEN - 1);

    if (z < 20) {
        // Q (z<16) or K (16..19): l2norm + rope -> T[128][72]
#pragma unroll
        for (int i = 0; i < 2; ++i) {
#pragma unroll
            for (int r = 0; r < 4; ++r) {
                const int row_l = w * 32 + i * 16 + quad * 4 + r;
                float v0 = acc[i][0][r], v1 = acc[i][1][r], v2 = acc[i][2][r], v3 = acc[i][3][r];
                float ss = v0 * v0 + v1 * v1 + v2 * v2 + v3 * v3;
                ss += __shfl_xor(ss, 1, 64);
                ss += __shfl_xor(ss, 2, 64);
                ss += __shfl_xor(ss, 4, 64);
                ss += __shfl_xor(ss, 8, 64);      // sum over the 16-lane (ln15) group
                const float inv = 1.f / (sqrtf(ss) + 1e-8f);
                const float n0 = v0 * inv, n1 = v1 * inv, n2 = v2 * inv, n3 = v3 * inv;
                const int spos = s0 + row_l;
                const float c0 = cosf[spos * 32 + ln15],      c1 = cosf[spos * 32 + 16 + ln15];
                const float sn0 = sinf[spos * 32 + ln15],     sn1 = sinf[spos * 32 + 16 + ln15];
                buf[row_l * 72 + ln15]      = f2bf(n0 * c0 - n2 * sn0);
                buf[row_l * 72 + 16 + ln15] = f2bf(n1 * c1 - n3 * sn1);
                buf[row_l * 72 + 32 + ln15] = f2bf(n0 * sn0 + n2 * c0);
                buf[row_l * 72 + 48 + ln15] = f2bf(n1 * sn1 + n3 * c1);
            }
        }
        __syncthreads();
        ushort* dst = (z < 16) ? Qb + ((size_t)(b * NHEADS + z) * SLEN + s0) * 64
                               : Kg + ((size_t)(b * NKV + (z - 16)) * SLEN + s0) * 64;
#pragma unroll
        for (int it = 0; it < 4; ++it) {
            const int c = it * 256 + tid;
            const int row = c >> 3, col = (c & 7) * 8;
            *reinterpret_cast<uint4*>(dst + (size_t)row * 64 + col) =
                *reinterpret_cast<const uint4*>(&buf[row * 72 + col]);
        }
    } else {
        // V: raw bf16, transposed stage T_v[64 d][136] -> coalesced rows of Vtg [d][2048]
#pragma unroll
        for (int i = 0; i < 2; ++i)
#pragma unroll
            for (int r = 0; r < 4; ++r) {
                const int row_l = w * 32 + i * 16 + quad * 4 + r;
#pragma unroll
                for (int j = 0; j < 4; ++j)
                    buf[(j * 16 + ln15) * 136 + row_l] = f2bf(acc[i][j][r]);
            }
        __syncthreads();
        ushort* dst = Vtg + ((size_t)(b * NKV + (z - 20)) * 64) * SLEN;
#pragma unroll
        for (int it = 0; it < 4; ++it) {
            const int c = it * 256 + tid;
            const int d = c >> 4, sb = (c & 15) * 8;
            *reinterpret_cast<uint4*>(dst + (size_t)d * SLEN + s0 + sb) =
                *reinterpret_cast<const uint4*>(&buf[d * 136 + sb]);
        }
    }
}

// ---------------- MFMA windowed flash attention, 64-key chunks ----------------
// Block = 64 queries of one (b,h): 4 waves x 16 q. Chunks of 64 keys over
// [align64(q0-255), q0+63] plus one global chunk (keys 0..3) when excluded.
// No running max: q,k unit vectors => |score*scale| <= 0.125, exp safe.
// softcap-exp: st = 15 - 30/(e^{2*sv/15}+1); p = exp(st). (|tanh arg| <= 0.0083)
__global__ __launch_bounds__(256) void attn_mfma(const ushort* __restrict__ Qb,
                                                 const ushort* __restrict__ Kg,
                                                 const ushort* __restrict__ Vtg,
                                                 ushort* __restrict__ ctx)
{
    __shared__ ushort Ks[64 * 72];      // [64 keys][64 dims], stride 72
    __shared__ ushort Vs[64 * 72];      // [64 dims][64 keys], stride 72
    __shared__ ushort Ps[4][16 * 72];   // per-wave P: [16 q][64 k], stride 72

    const int tid = threadIdx.x;
    const int lane = tid & 63, w = tid >> 6;
    const int ln15 = lane & 15, quad = lane >> 4;
    const int bid = blockIdx.x;
    const int qt = bid & 31, bh = bid >> 5;
    const int h = bh & (NHEADS - 1), b = bh >> 4, hkv = h >> 2;
    const int q0 = qt * 64;
    const int qw = q0 + w * 16;

    const ushort* Qrow = Qb + ((size_t)bh * SLEN + qw) * 64;
    const ushort* Kbase = Kg + (size_t)(b * NKV + hkv) * SLEN * 64;
    const ushort* Vbase = Vtg + (size_t)(b * NKV + hkv) * 64 * SLEN;

    short8 qf0 = *reinterpret_cast<const short8*>(Qrow + (size_t)ln15 * 64 + quad * 8);
    short8 qf1 = *reinterpret_cast<const short8*>(Qrow + (size_t)ln15 * 64 + 32 + quad * 8);

    floatx4 O0 = {0,0,0,0}, O1 = {0,0,0,0}, O2 = {0,0,0,0}, O3 = {0,0,0,0};
    float lp[4] = {0.f, 0.f, 0.f, 0.f};

    int kminA = q0 - (WINDOW - 1); if (kminA < 0) kminA = 0;
    kminA &= ~63;
    const int gmax = kminA < NGLOBAL ? kminA : NGLOBAL;
    const int nc = (q0 + 64 - kminA) >> 6;

    for (int c = (gmax > 0 ? -1 : 0); c < nc; ++c) {
        const int kbase = (c < 0) ? 0 : kminA + c * 64;
        __syncthreads();
#pragma unroll
        for (int j = 0; j < 2; ++j) {
            const int c2 = tid + j * 256;                 // chunk 0..511
            const int row = c2 >> 3, col = (c2 & 7) * 8;
            *reinterpret_cast<uint4*>(&Ks[row * 72 + col]) =
                *reinterpret_cast<const uint4*>(&Kbase[(size_t)(kbase + row) * 64 + col]);
            *reinterpret_cast<uint4*>(&Vs[row * 72 + col]) =
                *reinterpret_cast<const uint4*>(&Vbase[(size_t)row * SLEN + kbase + col]);
        }
        __syncthreads();

#pragma unroll
        for (int t = 0; t < 4; ++t) {
            short8 kf0 = *reinterpret_cast<const short8*>(&Ks[(t * 16 + ln15) * 72 + quad * 8]);
            short8 kf1 = *reinterpret_cast<const short8*>(&Ks[(t * 16 + ln15) * 72 + 32 + quad * 8]);
            floatx4 sc = {0,0,0,0};
            sc = __builtin_amdgcn_mfma_f32_16x16x32_bf16(qf0, kf0, sc, 0, 0, 0);
            sc = __builtin_amdgcn_mfma_f32_16x16x32_bf16(qf1, kf1, sc, 0, 0, 0);
            const int k = kbase + t * 16 + ln15;
#pragma unroll
            for (int r = 0; r < 4; ++r) {
                const int q = qw + quad * 4 + r;
                const bool valid = (c < 0) ? (k < gmax)
                                           : (k <= q && (k + WINDOW > q || k < NGLOBAL));
                float sv = sc[r] * 0.125f;                     // ATTN_SCALE
                float e2 = __expf(sv * 0.13333333f);           // e^{2*sv/15}
                float st = 15.f - 30.f * __builtin_amdgcn_rcpf(e2 + 1.f);
                ushort eb = valid ? f2bf(__expf(st)) : (ushort)0;
                Ps[w][(quad * 4 + r) * 72 + t * 16 + ln15] = eb;
                lp[r] += bf2f(eb);
            }
        }
        // P -> A-frag (in-wave LDS round trip; DS ops are in-order per wave)
        short8 af0 = *reinterpret_cast<const short8*>(&Ps[w][ln15 * 72 + quad * 8]);
        short8 af1 = *reinterpret_cast<const short8*>(&Ps[w][ln15 * 72 + 32 + quad * 8]);
#pragma unroll
        for (int n = 0; n < 4; ++n) {
            short8 vf0 = *reinterpret_cast<const short8*>(&Vs[(n * 16 + ln15) * 72 + quad * 8]);
            short8 vf1 = *reinterpret_cast<const short8*>(&Vs[(n * 16 + ln15) * 72 + 32 + quad * 8]);
            floatx4 On = (n == 0) ? O0 : (n == 1) ? O1 : (n == 2) ? O2 : O3;
            On = __builtin_amdgcn_mfma_f32_16x16x32_bf16(af0, vf0, On, 0, 0, 0);
            On = __builtin_amdgcn_mfma_f32_16x16x32_bf16(af1, vf1, On, 0, 0, 0);
            if (n == 0) O0 = On; else if (n == 1) O1 = On; else if (n == 2) O2 = On; else O3 = On;
        }
    }

#pragma unroll
    for (int r = 0; r < 4; ++r) {
#pragma unroll
        for (int off = 1; off < 16; off <<= 1)
            lp[r] += __shfl_xor(lp[r], off, 64);
        const float inv = __builtin_amdgcn_rcpf(lp[r]);
        const int q = qw + quad * 4 + r;
        ushort* crow = ctx + ((size_t)(b * SLEN + q)) * DMODEL + h * 64 + ln15;
        crow[0]  = f2bf(O0[r] * inv);
        crow[16] = f2bf(O1[r] * inv);
        crow[32] = f2bf(O2[r] * inv);
        crow[48] = f2bf(O3[r] * inv);
    }
}

// ---------------- out-proj GEMM: 128M x 64N tile, grid (16,32) = 512 blocks ----------------
__global__ __launch_bounds__(256) void gemm_out(const ushort* __restrict__ A,
                                                const ushort* __restrict__ Bt,
                                                void* __restrict__ out,
                                                const uint* __restrict__ cosu)
{
    __shared__ __align__(16) ushort buf[12288];
    ushort* lsA = buf;
    ushort* lsB = buf + 8192;
    const int tid = threadIdx.x;
    const int lane = tid & 63, w = tid >> 6;
    const int ln15 = lane & 15, quad = lane >> 4;
    const int rm = blockIdx.y * 128;
    const int cn = blockIdx.x * 64;

    floatx4 acc[2][4];
#pragma unroll
    for (int i = 0; i < 2; ++i)
#pragma unroll
        for (int j = 0; j < 4; ++j) acc[i][j] = (floatx4){0.f, 0.f, 0.f, 0.f};

    for (int k0 = 0; k0 < 1024; k0 += 64) {
        __syncthreads();
#pragma unroll
        for (int i = 0; i < 4; ++i) {
            const int c = (i * 4 + w) * 64 + lane;
            const int row = c >> 3, col = (c & 7) * 8;
            gload_lds16(&A[(size_t)(rm + row) * 1024 + k0 + col], &lsA[(i * 4 + w) * 512]);
        }
#pragma unroll
        for (int i = 0; i < 2; ++i) {
            const int c = (w * 2 + i) * 64 + lane;
            const int row = c >> 3, col = (c & 7) * 8;
            gload_lds16(&Bt[(size_t)(cn + row) * 1024 + k0 + col], &lsB[(w * 2 + i) * 512]);
        }
        __syncthreads();
#pragma unroll
        for (int kk = 0; kk < 64; kk += 32) {
            short8 af[2], bv[4];
#pragma unroll
            for (int i = 0; i < 2; ++i)
                af[i] = *reinterpret_cast<const short8*>(&lsA[(w * 32 + i * 16 + ln15) * 64 + kk + quad * 8]);
#pragma unroll
            for (int j = 0; j < 4; ++j)
                bv[j] = *reinterpret_cast<const short8*>(&lsB[(j * 16 + ln15) * 64 + kk + quad * 8]);
#pragma unroll
            for (int i = 0; i < 2; ++i)
#pragma unroll
                for (int j = 0; j < 4; ++j)
                    acc[i][j] = __builtin_amdgcn_mfma_f32_16x16x32_bf16(af[i], bv[j], acc[i][j], 0, 0, 0);
        }
    }

    const bool outbf = is_bf16_inputs(cosu);
#pragma unroll
    for (int i = 0; i < 2; ++i) {
#pragma unroll
        for (int r = 0; r < 4; ++r) {
            const int grow = rm + w * 32 + i * 16 + quad * 4 + r;
#pragma unroll
            for (int j = 0; j < 4; ++j) {
                const int gcol = cn + j * 16 + ln15;
                if (outbf) reinterpret_cast<ushort*>(out)[(size_t)grow * DMODEL + gcol] = f2bf(acc[i][j][r]);
                else       reinterpret_cast<float*>(out)[(size_t)grow * DMODEL + gcol] = acc[i][j][r];
            }
        }
    }
}

// ---------------- launch: 4 dispatches ----------------
extern "C" void kernel_launch(void* const* d_in, const int* in_sizes, int n_in,
                              void* d_out, int out_size, void* d_ws, size_t ws_size,
                              hipStream_t stream)
{
    (void)in_sizes; (void)n_in; (void)out_size; (void)ws_size;
    const void* x = d_in[0];
    const void* cosi = d_in[1];
    const void* sini = d_in[2];
    const uint* cosu = (const uint*)d_in[1];
    // d_in[3] = mask: computed analytically, not read
    const void* Wq = d_in[4];
    const void* Wk = d_in[5];
    const void* Wv = d_in[6];
    const void* Wo = d_in[7];

    // workspace (~34 MB)
    ushort* xb = (ushort*)d_ws;                        // [4096][1024] bf16
    ushort* Wt = xb + (size_t)4096 * 1024;             // [1536][1024] bf16 (Wq^T|Wk^T|Wv^T)
    ushort* Wot = Wt + (size_t)1536 * 1024;            // [1024][1024] bf16
    float* cosf = (float*)(Wot + (size_t)1024 * 1024); // [2048*32] f32
    float* sinf = cosf + (size_t)SLEN * 32;
    ushort* Qbf = (ushort*)(sinf + (size_t)SLEN * 32); // [2*16*2048][64] bf16
    ushort* Kgf = Qbf + (size_t)BATCH * NHEADS * SLEN * 64;    // [2*4*2048][64]
    ushort* Vtg = Kgf + (size_t)BATCH * NKV * SLEN * 64;       // [2*4][64][2048]
    ushort* ctx = Vtg + (size_t)BATCH * NKV * 64 * SLEN;       // [4096][1024]

    // 1) all canonicalization + weight transposes
    prep_all<<<dim3(5120), 256, 0, stream>>>(x, cosi, sini, Wq, Wk, Wv, Wo,
                                             xb, cosf, sinf, Wt, Wot, cosu);

    // 2) QKV projection + fused l2norm/RoPE/relayout (768 blocks)
    gemm_qkv_nr<<<dim3(24, 32), 256, 0, stream>>>(xb, Wt, cosf, sinf, Qbf, Kgf, Vtg);

    // 3) MFMA windowed attention (1024 blocks)
    attn_mfma<<<dim3(BATCH * NHEADS * SLEN / 64), 256, 0, stream>>>(Qbf, Kgf, Vtg, ctx);

    // 4) output projection -> d_out (512 blocks, dtype-matched)
    gemm_out<<<dim3(16, 32), 256, 0, stream>>>(ctx, Wot, d_out, cosu);
}